// Round 1
// 1596.190 us; speedup vs baseline: 1.5866x; 1.5866x over previous
//
#include <hip/hip_runtime.h>
#include <hip/hip_bf16.h>

// Problem constants: B=64, T=512, I=1024, H=1024 (fp32 in/out).
#define BB_   64
#define TT_   512
#define II_   1024
#define HH_   1024

typedef _Float16 half8  __attribute__((ext_vector_type(8)));
typedef _Float16 half4v __attribute__((ext_vector_type(4)));
typedef float    f32x4  __attribute__((ext_vector_type(4)));

// ---------------------------------------------------------------------------
// Phase 1: xp[b*T+t][j] = x[b,t,:] . W_ih[j,:] + b_ih[j], written to d_out.
// 128x128 tile, BK=32, f16 MFMA 16x16x32, in-staging fp32->f16 convert.
// (unchanged from previous round)
// ---------------------------------------------------------------------------
__global__ __launch_bounds__(256) void gemm_xp(const float* __restrict__ x,
                                               const float* __restrict__ Wih,
                                               const float* __restrict__ bih,
                                               float* __restrict__ out) {
    __shared__ alignas(16) _Float16 As[128 * 40];   // row stride 40 elems (80 B)
    __shared__ alignas(16) _Float16 Bs[128 * 40];

    const int tid  = threadIdx.x;
    const int bm   = blockIdx.x >> 3;              // 256 m-tiles
    const int bn   = blockIdx.x & 7;               // 8 n-tiles
    const int M0   = bm * 128, N0 = bn * 128;
    const int lane = tid & 63, w = tid >> 6;
    const int wm   = (w & 1) * 64, wn = (w >> 1) * 64;   // wave quadrant
    const int ro   = lane & 15, q = lane >> 4;
    const int sr   = tid >> 3, sc = tid & 7;       // staging: 32 rows x 8 chunks

    const f32x4 zero4 = {0.f, 0.f, 0.f, 0.f};
    f32x4 acc[4][4];
    #pragma unroll
    for (int i = 0; i < 4; ++i)
        #pragma unroll
        for (int j = 0; j < 4; ++j) acc[i][j] = zero4;

    for (int kk = 0; kk < 32; ++kk) {
        const int k0 = kk * 32;
        #pragma unroll
        for (int ir = 0; ir < 4; ++ir) {
            const int row = ir * 32 + sr;
            const float4 av = *(const float4*)(x   + (size_t)(M0 + row) * II_ + k0 + sc * 4);
            const float4 bv = *(const float4*)(Wih + (size_t)(N0 + row) * II_ + k0 + sc * 4);
            half4v ah = { (_Float16)av.x, (_Float16)av.y, (_Float16)av.z, (_Float16)av.w };
            half4v bh = { (_Float16)bv.x, (_Float16)bv.y, (_Float16)bv.z, (_Float16)bv.w };
            *(half4v*)(As + row * 40 + sc * 4) = ah;
            *(half4v*)(Bs + row * 40 + sc * 4) = bh;
        }
        __syncthreads();

        half8 a[4], b[4];
        #pragma unroll
        for (int i = 0; i < 4; ++i) {
            a[i] = *(const half8*)(As + (wm + i * 16 + ro) * 40 + q * 8);
            b[i] = *(const half8*)(Bs + (wn + i * 16 + ro) * 40 + q * 8);
        }
        #pragma unroll
        for (int i = 0; i < 4; ++i)
            #pragma unroll
            for (int j = 0; j < 4; ++j)
                acc[i][j] = __builtin_amdgcn_mfma_f32_16x16x32_f16(a[i], b[j], acc[i][j], 0, 0, 0);
        __syncthreads();
    }

    #pragma unroll
    for (int j = 0; j < 4; ++j) {
        const int col = N0 + wn + j * 16 + ro;
        const float bias = bih[col];
        #pragma unroll
        for (int i = 0; i < 4; ++i) {
            #pragma unroll
            for (int r = 0; r < 4; ++r) {
                const int rowg = M0 + wm + i * 16 + q * 4 + r;
                out[(size_t)rowg * HH_ + col] = acc[i][j][r] + bias;
            }
        }
    }
}

// ---------------------------------------------------------------------------
// Phase 2: persistent recurrence, tagged-word sync (seqlock-free).
//
// 256 WGs = 16 groups (4 batches each) x 16 WGs (64 cols each). Wave w of a
// WG owns 16 cols (j0 + w*16 .. +15) with the FULL K=1024 W_hh slice in
// VGPRs (wf[4 k-quarters][8] = 128 VGPRs) -> no cross-wave reduction, one
// __syncthreads per step.
//
// Cross-WG h exchange: comm word = {tag:16 | f16(h):16}, one relaxed
// agent-scope u32 per element. A single 32-bit load atomically returns
// tag+data, so consumers poll the data words directly -- no flags, no
// vmcnt(0) drain, no release fences on the critical path. Double-buffered
// by step parity: H_t lives in slot t&1 with tag t. Max producer/consumer
// skew is 1 step (step s needs ALL tag-s words => every WG finished its
// step s-1 reads), so slot reuse at distance 2 can never clobber a word
// still being polled. d_ws poison 0xAAAA never matches a valid tag 1..512.
// ---------------------------------------------------------------------------
__global__ __launch_bounds__(256, 1) void rnn_steps(const float* __restrict__ Whh,
                                                    const float* __restrict__ bhh,
                                                    const float* __restrict__ h0,
                                                    float* __restrict__ out,
                                                    unsigned* __restrict__ comm) {
    // [slot][row][col]: rows 0..3 = batches b0..b0+3 (f16 h), row 4 = zeros
    // (pads MFMA A rows 4..15). Row stride 1032 f16 = 2064 B -> the b128
    // A-reads start at bank 4*(row+q) mod 32: conflict-free.
    __shared__ alignas(16) _Float16 hbuf[2][5][1032];

    const int tid  = threadIdx.x;
    const int lane = tid & 63;
    const int w    = tid >> 6;             // wave id: stages batch w, owns 16 cols
    const int g    = blockIdx.x >> 4;      // group 0..15
    const int wg   = blockIdx.x & 15;      // wg within group
    const int b0   = g * 4;
    const int j0   = wg * 64;
    const int ro   = lane & 15, q = lane >> 4;
    const int arow  = (ro < 4) ? ro : 4;   // A rows >=4 read the shared zero row
    const int mycol = j0 + w * 16 + ro;    // this lane's output column (q==0 lanes)

    // Preload W_hh B-fragments for the full K: wf[kq][ks][e] =
    // Whh[mycol][kq*256 + ks*32 + q*8 + e]  (B[n=ro][k], n-major per wave).
    half8 wf[4][8];
    {
        const float* wrow = Whh + (size_t)mycol * HH_;
        #pragma unroll
        for (int kq = 0; kq < 4; ++kq) {
            #pragma unroll
            for (int ks = 0; ks < 8; ++ks) {
                const int kc = kq * 256 + ks * 32 + q * 8;
                const float4 w0 = *(const float4*)(wrow + kc);
                const float4 w1 = *(const float4*)(wrow + kc + 4);
                half8 hv;
                hv[0] = (_Float16)w0.x; hv[1] = (_Float16)w0.y;
                hv[2] = (_Float16)w0.z; hv[3] = (_Float16)w0.w;
                hv[4] = (_Float16)w1.x; hv[5] = (_Float16)w1.y;
                hv[6] = (_Float16)w1.z; hv[7] = (_Float16)w1.w;
                wf[kq][ks] = hv;
            }
        }
    }
    const float bhh_r = bhh[mycol];

    // zero row 4 of both LDS slots (shared MFMA zero-pad row)
    for (int i = tid; i < 1032; i += 256) {
        hbuf[0][4][i] = (_Float16)0.f;
        hbuf[1][4][i] = (_Float16)0.f;
    }

    const f32x4 zero4 = {0.f, 0.f, 0.f, 0.f};

    for (int s = 0; s < TT_; ++s) {
        const int slot = s & 1;

        // xp prefetch (own output address, overwritten by self later). Plain
        // load: issued before the poll so HBM latency hides under it.
        float xpv[4];
        if (q == 0) {
            #pragma unroll
            for (int r = 0; r < 4; ++r)
                xpv[r] = out[((size_t)(b0 + r) * TT_ + s) * HH_ + mycol];
        }

        // ---- stage h_{s} (input state) into hbuf[slot][w][:] ----
        _Float16* dst = &hbuf[slot][w][0];
        if (s == 0) {
            const float* hrow = h0 + (size_t)(b0 + w) * HH_;
            #pragma unroll
            for (int i = 0; i < 16; ++i)
                dst[i * 64 + lane] = (_Float16)hrow[i * 64 + lane];
        } else {
            // poll own 16 comm words (coalesced 256B per wave-load); retry
            // only the stale ones. Word tag==s means it holds H_s.
            unsigned* src = comm + (size_t)slot * (BB_ * HH_) + (size_t)(b0 + w) * HH_;
            unsigned v[16];
            #pragma unroll
            for (int i = 0; i < 16; ++i) v[i] = 0u;
            bool ok = false;
            while (!ok) {
                ok = true;
                #pragma unroll
                for (int i = 0; i < 16; ++i) {
                    if ((v[i] >> 16) != (unsigned)s) {
                        v[i] = __hip_atomic_load(src + i * 64 + lane,
                                                 __ATOMIC_RELAXED,
                                                 __HIP_MEMORY_SCOPE_AGENT);
                        ok = false;
                    }
                }
            }
            #pragma unroll
            for (int i = 0; i < 16; ++i) {
                union { unsigned short u; _Float16 h; } cv;
                cv.u = (unsigned short)(v[i] & 0xffffu);
                dst[i * 64 + lane] = cv.h;   // ds_write_b16, 2-way = free
            }
        }
        __syncthreads();   // the only barrier per step (LDS double-buffered)

        // ---- MFMA: this wave's 16 cols x full K=1024, 4 independent chains
        f32x4 acc[4] = {zero4, zero4, zero4, zero4};
        const _Float16* abase = &hbuf[slot][0][0] + (size_t)arow * 1032;
        #pragma unroll
        for (int kq = 0; kq < 4; ++kq) {
            #pragma unroll
            for (int ks = 0; ks < 8; ++ks) {
                const half8 a = *(const half8*)(abase + kq * 256 + ks * 32 + q * 8);
                acc[kq] = __builtin_amdgcn_mfma_f32_16x16x32_f16(a, wf[kq][ks], acc[kq], 0, 0, 0);
            }
        }

        // ---- epilogue: D row=q*4+r (batch, valid q==0), col=ro ----
        if (q == 0) {
            const unsigned tag = (unsigned)(s + 1) << 16;
            unsigned* cdst = comm + (size_t)((s + 1) & 1) * (BB_ * HH_);
            #pragma unroll
            for (int r = 0; r < 4; ++r) {
                const float pre  = xpv[r] + bhh_r
                                 + acc[0][r] + acc[1][r] + acc[2][r] + acc[3][r];
                const float hnew = tanhf(pre);
                // fp32 result for final output: plain cached store.
                out[((size_t)(b0 + r) * TT_ + s) * HH_ + mycol] = hnew;
                // tagged f16 broadcast word: fire-and-forget, no drain.
                union { _Float16 h; unsigned short u; } cv; cv.h = (_Float16)hnew;
                __hip_atomic_store(cdst + (size_t)(b0 + r) * HH_ + mycol,
                                   tag | (unsigned)cv.u, __ATOMIC_RELAXED,
                                   __HIP_MEMORY_SCOPE_AGENT);
            }
        }
        // no trailing barrier: next step stages into hbuf[slot^1]; slot reuse
        // at distance 2 is ordered by the step s+1 __syncthreads.
    }
}

// ---------------------------------------------------------------------------
extern "C" void kernel_launch(void* const* d_in, const int* in_sizes, int n_in,
                              void* d_out, int out_size, void* d_ws, size_t ws_size,
                              hipStream_t stream) {
    (void)in_sizes; (void)n_in; (void)out_size; (void)ws_size;

    const float* x   = (const float*)d_in[0];
    const float* h0  = (const float*)d_in[1];
    const float* Wih = (const float*)d_in[2];
    const float* bih = (const float*)d_in[3];
    const float* Whh = (const float*)d_in[4];
    const float* bhh = (const float*)d_in[5];
    float* out = (float*)d_out;

    // d_ws: tagged h comm buffer -- 2 slots x 64 x 1024 u32 = 512 KB.
    // Poison 0xAAAAAAAA => tag 0xAAAA, never equals a valid tag 1..512.
    unsigned* comm = (unsigned*)d_ws;

    gemm_xp<<<2048, 256, 0, stream>>>(x, Wih, bih, out);
    rnn_steps<<<256, 256, 0, stream>>>(Whh, bhh, h0, out, comm);
}